// Round 12
// baseline (182.918 us; speedup 1.0000x reference)
//
#include <hip/hip_runtime.h>

#define N_NODES 8192
#define N_EDGES 262144
#define NFEAT 200
#define NHID 128

__device__ __forceinline__ float aload(const float* p) {
    return __hip_atomic_load(p, __ATOMIC_RELAXED, __HIP_MEMORY_SCOPE_AGENT);
}

// ---------------- GEMM body: C[8 rows,128] = A[8,K] @ W[128,K]^T ----------------
template<int K>
__device__ __forceinline__ void gemm_body(const float* __restrict__ A,
                                          const float* __restrict__ W,
                                          float* __restrict__ C, int bid) {
    __shared__ float a_s[8 * K];
    int row0 = bid * 8;
    const float* Ab = A + (size_t)row0 * K;
    for (int idx = threadIdx.x; idx < 8 * K; idx += 128) a_s[idx] = Ab[idx];
    __syncthreads();
    int j = threadIdx.x;
    float acc[8] = {0.f, 0.f, 0.f, 0.f, 0.f, 0.f, 0.f, 0.f};
    const float4* W4 = (const float4*)(W + (size_t)j * K);
    for (int k4 = 0; k4 < K / 4; ++k4) {
        float4 w = W4[k4];
        int k = k4 * 4;
        #pragma unroll
        for (int r = 0; r < 8; ++r) {
            const float* ar = a_s + r * K + k;
            acc[r] += ar[0] * w.x + ar[1] * w.y + ar[2] * w.z + ar[3] * w.w;
        }
    }
    #pragma unroll
    for (int r = 0; r < 8; ++r) C[(size_t)(row0 + r) * 128 + j] = acc[r];
}

template<int K>
__global__ __launch_bounds__(128) void gemm_rows(const float* __restrict__ A,
                                                 const float* __restrict__ W,
                                                 float* __restrict__ C) {
    gemm_body<K>(A, W, C, blockIdx.x);
}

// fused: blocks [0,512) gemm layer-1 (16 rows each); blocks [512,576) dst histogram
__global__ __launch_bounds__(128) void gemm1_hist(const float* __restrict__ A,
                                                  const float* __restrict__ W,
                                                  float* __restrict__ C,
                                                  const int* __restrict__ ei,
                                                  int* __restrict__ deg) {
    if (blockIdx.x < N_NODES / 16) {
        __shared__ float a_s[16 * NFEAT];
        int row0 = blockIdx.x * 16;
        const float* Ab = A + (size_t)row0 * NFEAT;
        for (int idx = threadIdx.x; idx < 16 * NFEAT; idx += 128) a_s[idx] = Ab[idx];
        __syncthreads();
        int j = threadIdx.x;
        float acc[16];
        #pragma unroll
        for (int r = 0; r < 16; ++r) acc[r] = 0.f;
        const float4* W4 = (const float4*)(W + (size_t)j * NFEAT);
        for (int k4 = 0; k4 < NFEAT / 4; ++k4) {
            float4 w = W4[k4];
            int k = k4 * 4;
            #pragma unroll
            for (int r = 0; r < 16; ++r) {
                const float* ar = a_s + r * NFEAT + k;
                acc[r] += ar[0] * w.x + ar[1] * w.y + ar[2] * w.z + ar[3] * w.w;
            }
        }
        #pragma unroll
        for (int r = 0; r < 16; ++r)
            C[(size_t)(row0 + r) * 128 + j] = acc[r];
    } else {
        const int* dst = ei + N_EDGES;
        for (int e = (blockIdx.x - N_NODES / 16) * 128 + threadIdx.x; e < N_EDGES; e += 64 * 128)
            atomicAdd(&deg[dst[e]], 1);
    }
}

// ---- merged: block 0 = prefix scan (then release flag); blocks 1..1024 = scatter ----
__global__ __launch_bounds__(256) void scan_scatter(const int* __restrict__ deg,
                                                    int* __restrict__ row_start,
                                                    int* __restrict__ cursor,
                                                    const int* __restrict__ ei,
                                                    const float* __restrict__ ew,
                                                    int2* __restrict__ esort,
                                                    int* __restrict__ sync_flag) {
    __shared__ int part[256];
    __shared__ int partx[257];
    int tid = threadIdx.x;
    if (blockIdx.x == 0) {
        int base = tid * 32;
        int s = 0;
        for (int i = 0; i < 32; ++i) s += deg[base + i];
        part[tid] = s;
        __syncthreads();
        if (tid == 0) {
            int run = 0;
            for (int i = 0; i < 256; ++i) { partx[i] = run; run += part[i]; }
            partx[256] = run;
        }
        __syncthreads();
        int run = partx[tid];
        for (int i = 0; i < 32; ++i) {
            row_start[base + i] = run;
            cursor[base + i] = run;
            run += deg[base + i];
        }
        if (tid == 255) row_start[N_NODES] = run;
        __syncthreads();
        if (tid == 0)   // release: flush scan's stores to coherent point, then publish
            __hip_atomic_store(sync_flag, 1, __ATOMIC_RELEASE, __HIP_MEMORY_SCOPE_AGENT);
    } else {
        if (tid == 0) {
            while (!__hip_atomic_load(sync_flag, __ATOMIC_RELAXED, __HIP_MEMORY_SCOPE_AGENT))
                __builtin_amdgcn_s_sleep(2);
        }
        __syncthreads();
        // cursor accessed only via L2 atomics -> sees scan's released values
        int e = (blockIdx.x - 1) * 256 + tid;
        int d = ei[N_EDGES + e];
        int pos = atomicAdd(&cursor[d], 1);
        esort[pos] = make_int2(ei[e], __float_as_int(ew[e]));
    }
}

// weighted CSR gather, lane-parallel edge prefetch + shuffle broadcast
__device__ __forceinline__ float2 csr_gather(const int* __restrict__ row_start,
                                             const int2* __restrict__ esort,
                                             const float* __restrict__ H,
                                             int row, int lane) {
    int s0 = row_start[row], s1 = row_start[row + 1];
    float ax0 = 0.f, ay0 = 0.f, ax1 = 0.f, ay1 = 0.f;
    float ax2 = 0.f, ay2 = 0.f, ax3 = 0.f, ay3 = 0.f;
    for (int base = s0; base < s1; base += 64) {
        int n = s1 - base;
        if (n > 64) n = 64;
        int2 meta = make_int2(0, 0);
        if (lane < n) meta = esort[base + lane];
        int k = 0;
        for (; k + 3 < n; k += 4) {
            int sA = __shfl(meta.x, k, 64);
            int sB = __shfl(meta.x, k + 1, 64);
            int sC = __shfl(meta.x, k + 2, 64);
            int sD = __shfl(meta.x, k + 3, 64);
            float wA = __int_as_float(__shfl(meta.y, k, 64));
            float wB = __int_as_float(__shfl(meta.y, k + 1, 64));
            float wC = __int_as_float(__shfl(meta.y, k + 2, 64));
            float wD = __int_as_float(__shfl(meta.y, k + 3, 64));
            float2 vA = *(const float2*)(H + (size_t)sA * 128 + lane * 2);
            float2 vB = *(const float2*)(H + (size_t)sB * 128 + lane * 2);
            float2 vC = *(const float2*)(H + (size_t)sC * 128 + lane * 2);
            float2 vD = *(const float2*)(H + (size_t)sD * 128 + lane * 2);
            ax0 += wA * vA.x; ay0 += wA * vA.y;
            ax1 += wB * vB.x; ay1 += wB * vB.y;
            ax2 += wC * vC.x; ay2 += wC * vC.y;
            ax3 += wD * vD.x; ay3 += wD * vD.y;
        }
        for (; k < n; ++k) {
            int sA = __shfl(meta.x, k, 64);
            float wA = __int_as_float(__shfl(meta.y, k, 64));
            float2 vA = *(const float2*)(H + (size_t)sA * 128 + lane * 2);
            ax0 += wA * vA.x; ay0 += wA * vA.y;
        }
    }
    return make_float2((ax0 + ax1) + (ax2 + ax3), (ay0 + ay1) + (ay2 + ay3));
}

// bias + LayerNorm + relu on a wave-held row (2 dims/lane)
__device__ __forceinline__ float2 ln_relu(float vx, float vy, int lane,
                                          const float* __restrict__ bias,
                                          const float* __restrict__ g,
                                          const float* __restrict__ b) {
    float2 bs = *(const float2*)(bias + lane * 2);
    vx += bs.x; vy += bs.y;
    float s = vx + vy, ss = vx * vx + vy * vy;
    for (int off = 32; off; off >>= 1) {
        s += __shfl_xor(s, off, 64);
        ss += __shfl_xor(ss, off, 64);
    }
    float mu = s * (1.f / 128.f);
    float var = ss * (1.f / 128.f) - mu * mu;
    float rs = rsqrtf(var + 1e-5f);
    float2 gg = *(const float2*)(g + lane * 2);
    float2 bb = *(const float2*)(b + lane * 2);
    return make_float2(fmaxf((vx - mu) * rs * gg.x + bb.x, 0.f),
                       fmaxf((vy - mu) * rs * gg.y + bb.y, 0.f));
}

// ---------------- out[i] = relu(LN(agg(H)+bias)), one wave per row ----------------
__global__ __launch_bounds__(256) void agg_ln_csr(const int* __restrict__ row_start,
                                                  const int2* __restrict__ esort,
                                                  const float* __restrict__ H,
                                                  float* __restrict__ out,
                                                  const float* __restrict__ bias,
                                                  const float* __restrict__ g,
                                                  const float* __restrict__ b) {
    int wave = (blockIdx.x * blockDim.x + threadIdx.x) >> 6;
    int lane = threadIdx.x & 63;
    float2 a = csr_gather(row_start, esort, H, wave, lane);
    float2 y = ln_relu(a.x, a.y, lane, bias, g, b);
    *(float2*)(out + (size_t)wave * 128 + lane * 2) = y;
}

// ---------------- fused: latent = relu(LN(agg(bufC)+b)); pool0 c0; LDS xc0 partials ----
__global__ __launch_bounds__(1024) void agg2_pool0(const int* __restrict__ row_start,
                                                   const int2* __restrict__ esort,
                                                   const float* __restrict__ bufC,
                                                   float* __restrict__ latent,
                                                   const float* __restrict__ bias,
                                                   const float* __restrict__ g,
                                                   const float* __restrict__ b,
                                                   const float* __restrict__ p0W,
                                                   const float* __restrict__ p0b,
                                                   const float* __restrict__ gum,
                                                   int* __restrict__ c0,
                                                   float* __restrict__ partials) {
    __shared__ float Ws[1280];
    __shared__ float accs[1280];
    __shared__ float bsh[10];
    int tid = threadIdx.x;
    for (int i = tid; i < 1280; i += 1024) { Ws[i] = p0W[i]; accs[i] = 0.f; }
    if (tid < 10) bsh[tid] = p0b[tid];
    __syncthreads();
    int lane = tid & 63, wid = tid >> 6;
    int row = blockIdx.x * 16 + wid;
    float2 a = csr_gather(row_start, esort, bufC, row, lane);
    float2 y = ln_relu(a.x, a.y, lane, bias, g, b);
    *(float2*)(latent + (size_t)row * 128 + lane * 2) = y;
    float pk[10];
    #pragma unroll
    for (int k = 0; k < 10; ++k)
        pk[k] = y.x * Ws[k * 128 + lane * 2] + y.y * Ws[k * 128 + lane * 2 + 1];
    for (int off = 32; off; off >>= 1) {
        #pragma unroll
        for (int k = 0; k < 10; ++k) pk[k] += __shfl_xor(pk[k], off, 64);
    }
    const float* gr = gum + (size_t)row * 10;
    int best = 0;
    float bv = pk[0] + bsh[0] + gr[0];
    #pragma unroll
    for (int k = 1; k < 10; ++k) {
        float z = pk[k] + bsh[k] + gr[k];
        if (z > bv) { bv = z; best = k; }   // first max wins (jnp.argmax)
    }
    if (lane == 0) c0[row] = best;
    atomicAdd(&accs[best * 128 + lane * 2], y.x);
    atomicAdd(&accs[best * 128 + lane * 2 + 1], y.y);
    __syncthreads();
    for (int i = tid; i < 1280; i += 1024)
        partials[(size_t)blockIdx.x * 1280 + i] = accs[i];
}

// ---- merged: blocks [0,256) A0 pool; [256,266) xc0 reduce; block 266 waits -> solver ----
__global__ __launch_bounds__(256) void adjxc0_small(const int* __restrict__ ei,
                                                    const float* __restrict__ ew,
                                                    const int* __restrict__ c0,
                                                    float* __restrict__ A0,
                                                    const float* __restrict__ partials,
                                                    float* __restrict__ xc0,
                                                    int* __restrict__ done,
                                                    const float* __restrict__ gum1,
                                                    const float* __restrict__ p1W,
                                                    const float* __restrict__ p1b,
                                                    const float* __restrict__ e0W,
                                                    const float* __restrict__ e0b,
                                                    const float* __restrict__ e1W,
                                                    const float* __restrict__ e1b,
                                                    const float* __restrict__ fcW,
                                                    const float* __restrict__ fcb,
                                                    float* __restrict__ tbl) {
    __shared__ float Wst[64 * 129];
    __shared__ float xc0n[10 * 128];
    __shared__ float adj0[100];
    __shared__ float m0[10 * 128];
    __shared__ float l1[10 * 128];
    __shared__ float xc1n[5 * 128];
    __shared__ float l2[5 * 128];
    __shared__ float A1[25];
    __shared__ float lg[50];
    __shared__ float As[100];
    __shared__ float sm[256];
    __shared__ int c1[10];
    __shared__ float red[4];

    int tid = threadIdx.x;
    int wid = tid >> 6, lane = tid & 63;

    if (blockIdx.x < 256) {
        // ---- A0 edge pool ----
        for (int i = tid; i < 100; i += 256) As[i] = 0.f;
        __syncthreads();
        for (int e = blockIdx.x * 256 + tid; e < N_EDGES; e += 256 * 256) {
            int a = c0[ei[e]], b = c0[ei[N_EDGES + e]];
            atomicAdd(&As[a * 10 + b], ew[e]);
        }
        __syncthreads();
        for (int i = tid; i < 100; i += 256) atomicAdd(&A0[i], As[i]);
        __syncthreads();
        if (tid == 0)
            __hip_atomic_fetch_add(done, 1, __ATOMIC_RELEASE, __HIP_MEMORY_SCOPE_AGENT);
        return;
    }
    if (blockIdx.x < 266) {
        // ---- xc0 reduce over 512 partial sets (atomicAdd -> coherent point) ----
        int k = blockIdx.x - 256;
        int d = tid & 127, half = tid >> 7;
        float s0 = 0.f, s1 = 0.f, s2 = 0.f, s3 = 0.f;
        for (int b = half * 256; b < half * 256 + 256; b += 4) {
            s0 += partials[(size_t)(b    ) * 1280 + k * 128 + d];
            s1 += partials[(size_t)(b + 1) * 1280 + k * 128 + d];
            s2 += partials[(size_t)(b + 2) * 1280 + k * 128 + d];
            s3 += partials[(size_t)(b + 3) * 1280 + k * 128 + d];
        }
        sm[tid] = (s0 + s1) + (s2 + s3);
        __syncthreads();
        if (tid < 128) atomicAdd(&xc0[k * 128 + d], sm[tid] + sm[tid + 128]);
        __syncthreads();
        if (tid == 0)
            __hip_atomic_fetch_add(done, 1, __ATOMIC_RELEASE, __HIP_MEMORY_SCOPE_AGENT);
        return;
    }

    // ---- solver block: wait for all 266 producers ----
    if (tid == 0) {
        while (__hip_atomic_load(done, __ATOMIC_RELAXED, __HIP_MEMORY_SCOPE_AGENT) != 266)
            __builtin_amdgcn_s_sleep(2);
    }
    __syncthreads();
    __builtin_amdgcn_fence(__ATOMIC_ACQUIRE, "agent");

    // xc0 row-normalize (agent-scope atomic loads: values live at coherent point)
    for (int r = wid; r < 10; r += 4) {
        float vx = aload(xc0 + r * 128 + lane * 2);
        float vy = aload(xc0 + r * 128 + lane * 2 + 1);
        float ss = vx * vx + vy * vy;
        for (int off = 32; off; off >>= 1) ss += __shfl_xor(ss, off, 64);
        float sc = 1.f / fmaxf(sqrtf(ss), 1e-12f);
        xc0n[r * 128 + lane * 2] = vx * sc;
        xc0n[r * 128 + lane * 2 + 1] = vy * sc;
    }
    __syncthreads();
    if (tid == 0) {
        float s = 0.f;
        for (int i = 0; i < 100; ++i) s += aload(A0 + i);
        red[0] = s + 1e-6f;
    }
    __syncthreads();
    if (tid < 100) adj0[tid] = aload(A0 + tid) / red[0];
    __syncthreads();
    // m0 = adj0 @ xc0n
    for (int idx = tid; idx < 1280; idx += 256) {
        int r = idx >> 7, d = idx & 127;
        float acc = 0.f;
        #pragma unroll
        for (int a = 0; a < 10; ++a) acc += adj0[r * 10 + a] * xc0n[a * 128 + d];
        m0[idx] = acc;
    }
    __syncthreads();
    // l1 = relu(m0 @ e0W^T + e0b), staged halves (stride 129)
    for (int h = 0; h < 2; ++h) {
        for (int i = tid; i < 64 * 128; i += 256)
            Wst[(i >> 7) * 129 + (i & 127)] = e0W[(size_t)(h * 64) * 128 + i];
        __syncthreads();
        for (int idx = tid; idx < 640; idx += 256) {
            int r = idx >> 6, dd = idx & 63;
            int d = h * 64 + dd;
            float acc = e0b[d];
            const float* wrow = Wst + dd * 129;
            const float* mr = m0 + r * 128;
            for (int k = 0; k < 128; ++k) acc += mr[k] * wrow[k];
            l1[r * 128 + d] = fmaxf(acc, 0.f);
        }
        __syncthreads();
    }
    // logits1 (50-thread parallel) + gumbel -> c1
    for (int i = tid; i < 640; i += 256) Wst[i] = p1W[i];
    __syncthreads();
    if (tid < 50) {
        int k = tid / 5, j = tid % 5;
        float acc = p1b[j] + gum1[k * 5 + j];
        const float* wrow = Wst + j * 128;
        const float* lr = l1 + k * 128;
        for (int kk = 0; kk < 128; ++kk) acc += lr[kk] * wrow[kk];
        lg[tid] = acc;
    }
    __syncthreads();
    if (tid < 10) {
        int best = 0;
        float bv = lg[tid * 5];
        for (int j = 1; j < 5; ++j) {
            float z = lg[tid * 5 + j];
            if (z > bv) { bv = z; best = j; }
        }
        c1[tid] = best;
    }
    __syncthreads();
    // xc1 = segsum(l1 by c1)
    for (int idx = tid; idx < 640; idx += 256) {
        int m = idx >> 7, d = idx & 127;
        float acc = 0.f;
        #pragma unroll
        for (int k = 0; k < 10; ++k)
            if (c1[k] == m) acc += l1[k * 128 + d];
        xc1n[idx] = acc;
    }
    __syncthreads();
    for (int r = wid; r < 5; r += 4) {
        float2 v = *(const float2*)(xc1n + r * 128 + lane * 2);
        float ss = v.x * v.x + v.y * v.y;
        for (int off = 32; off; off >>= 1) ss += __shfl_xor(ss, off, 64);
        float sc = 1.f / fmaxf(sqrtf(ss), 1e-12f);
        xc1n[r * 128 + lane * 2] = v.x * sc;
        xc1n[r * 128 + lane * 2 + 1] = v.y * sc;
    }
    __syncthreads();
    if (tid < 25) {
        int m = tid / 5, n = tid % 5;
        float acc = 0.f;
        for (int a = 0; a < 10; ++a)
            for (int b = 0; b < 10; ++b)
                if (c1[a] == m && c1[b] == n) acc += adj0[a * 10 + b];
        A1[tid] = acc;
    }
    __syncthreads();
    if (tid == 0) {
        float s = 0.f;
        for (int i = 0; i < 25; ++i) s += A1[i];
        red[1] = s + 25e-8f;
    }
    __syncthreads();
    float den1 = red[1];
    for (int idx = tid; idx < 640; idx += 256) {
        int r = idx >> 7, d = idx & 127;
        float acc = 0.f;
        #pragma unroll
        for (int a = 0; a < 5; ++a) acc += A1[r * 5 + a] * xc1n[a * 128 + d];
        m0[idx] = acc / den1;
    }
    __syncthreads();
    // l2 = relu(m1 @ e1W^T + e1b), staged halves
    for (int h = 0; h < 2; ++h) {
        for (int i = tid; i < 64 * 128; i += 256)
            Wst[(i >> 7) * 129 + (i & 127)] = e1W[(size_t)(h * 64) * 128 + i];
        __syncthreads();
        for (int idx = tid; idx < 320; idx += 256) {
            int r = idx >> 6, dd = idx & 63;
            int d = h * 64 + dd;
            float acc = e1b[d];
            const float* wrow = Wst + dd * 129;
            const float* mr = m0 + r * 128;
            for (int k = 0; k < 128; ++k) acc += mr[k] * wrow[k];
            l2[r * 128 + d] = fmaxf(acc, 0.f);
        }
        __syncthreads();
    }
    // stage fcW[:,128:384] as [16][257]
    for (int i = tid; i < 16 * 256; i += 256) {
        int o = i >> 8, k2 = i & 255;
        Wst[o * 257 + k2] = fcW[o * 384 + 128 + k2];
    }
    __syncthreads();
    for (int idx = tid; idx < 160; idx += 256) {
        int k = idx >> 4, o = idx & 15;
        float acc = fcb[o];
        const float* fB = Wst + o * 257;
        const float* fC = Wst + o * 257 + 128;
        const float* a1 = l1 + k * 128;
        const float* a2 = l2 + c1[k] * 128;
        for (int d = 0; d < 128; ++d) acc += a1[d] * fB[d] + a2[d] * fC[d];
        tbl[idx] = acc;
    }
}

// ---------------- out[i] = latent[i] @ fcA^T + tbl[c0[i]], 8-lane groups ----------------
__global__ __launch_bounds__(256) void out_kernel(const float* __restrict__ latent,
                                                  const int* __restrict__ c0,
                                                  const float* __restrict__ tbl,
                                                  const float* __restrict__ fcW,
                                                  float* __restrict__ out) {
    __shared__ float fA[16 * 128];
    __shared__ float ts[160];
    for (int i = threadIdx.x; i < 2048; i += 256) {
        int o = i >> 7, d = i & 127;
        fA[i] = fcW[o * 384 + d];
    }
    for (int i = threadIdx.x; i < 160; i += 256) ts[i] = tbl[i];
    __syncthreads();
    int lane = threadIdx.x & 63;
    int sub = lane & 7;
    int row = blockIdx.x * 32 + (threadIdx.x >> 6) * 8 + (lane >> 3);
    const float4* lp = (const float4*)(latent + (size_t)row * 128 + sub * 16);
    float4 x0 = lp[0], x1 = lp[1], x2 = lp[2], x3 = lp[3];
    float p[16];
    #pragma unroll
    for (int o = 0; o < 16; ++o) {
        const float4* fo = (const float4*)(fA + o * 128 + sub * 16);
        float4 w0 = fo[0], w1 = fo[1], w2 = fo[2], w3 = fo[3];
        float a = x0.x * w0.x + x0.y * w0.y + x0.z * w0.z + x0.w * w0.w;
        a += x1.x * w1.x + x1.y * w1.y + x1.z * w1.z + x1.w * w1.w;
        a += x2.x * w2.x + x2.y * w2.y + x2.z * w2.z + x2.w * w2.w;
        a += x3.x * w3.x + x3.y * w3.y + x3.z * w3.z + x3.w * w3.w;
        p[o] = a;
    }
    #pragma unroll
    for (int off = 1; off < 8; off <<= 1) {
        #pragma unroll
        for (int o = 0; o < 16; ++o) p[o] += __shfl_xor(p[o], off, 64);
    }
    int c = c0[row];
    float2 r = make_float2(p[2 * sub] + ts[c * 16 + 2 * sub],
                           p[2 * sub + 1] + ts[c * 16 + 2 * sub + 1]);
    *(float2*)(out + (size_t)row * 16 + 2 * sub) = r;
}

extern "C" void kernel_launch(void* const* d_in, const int* in_sizes, int n_in,
                              void* d_out, int out_size, void* d_ws, size_t ws_size,
                              hipStream_t stream) {
    const float* x    = (const float*)d_in[0];
    const int*   ei   = (const int*)d_in[1];
    const float* ew   = (const float*)d_in[2];
    const float* g0   = (const float*)d_in[3];
    const float* g1   = (const float*)d_in[4];
    const float* Wg1  = (const float*)d_in[5];
    const float* bg1  = (const float*)d_in[6];
    const float* ln1g = (const float*)d_in[7];
    const float* ln1b = (const float*)d_in[8];
    const float* Wg2  = (const float*)d_in[9];
    const float* bg2  = (const float*)d_in[10];
    const float* ln2g = (const float*)d_in[11];
    const float* ln2b = (const float*)d_in[12];
    const float* p0W  = (const float*)d_in[13];
    const float* p0b  = (const float*)d_in[14];
    const float* p1W  = (const float*)d_in[15];
    const float* p1b  = (const float*)d_in[16];
    const float* e0W  = (const float*)d_in[17];
    const float* e0b  = (const float*)d_in[18];
    const float* e1W  = (const float*)d_in[19];
    const float* e1b  = (const float*)d_in[20];
    const float* fcW  = (const float*)d_in[21];
    const float* fcb  = (const float*)d_in[22];
    float* out = (float*)d_out;

    float* ws   = (float*)d_ws;
    float* bufA = ws;                                        // N*128 f (gemm1 out)
    float* bufB = bufA + (size_t)N_NODES * 128;              // N*128 f (latent / h1)
    float* bufC = bufB + (size_t)N_NODES * 128;              // N*128 f (gemm2 out)
    int*   c0   = (int*)(bufC + (size_t)N_NODES * 128);      // N int
    float* tbl  = (float*)(c0 + N_NODES);                    // 160 f
    int*   deg  = (int*)(tbl + 160);                         // 8192 int <- memset start
    float* A0   = (float*)(deg + N_NODES);                   // 100 f
    float* xc0  = A0 + 100;                                  // 1280 f (atomic-accumulated)
    int*   sync = (int*)(xc0 + 1280);                        // [0]=scan flag, [1]=done  <- memset end
    int*   row_start = sync + 2;                             // 8194 int
    int*   cursor    = row_start + N_NODES + 2;              // 8192 int
    int2*  esort     = (int2*)(cursor + N_NODES);            // E int2
    float* partials  = bufA;   // 512*1280 f, reuses bufA (dead after gemm2)

    // zero deg + A0 + xc0 + sync flags in one fill
    hipMemsetAsync(deg, 0, (N_NODES + 100 + 1280 + 2) * sizeof(int), stream);

    // layer-1 gemm (16 rows/block; agg commutes) fused with dst-histogram
    gemm1_hist<<<N_NODES / 16 + 64, 128, 0, stream>>>(x, Wg1, bufA, ei, deg);
    // scan (block 0) + scatter (blocks 1..1024), single-producer flag sync
    scan_scatter<<<1025, 256, 0, stream>>>(deg, row_start, cursor, ei, ew, esort, sync);

    // agg1 + LN + relu -> bufB (h1)
    agg_ln_csr<<<N_NODES / 4, 256, 0, stream>>>(row_start, esort, bufA, bufB,
                                                bg1, ln1g, ln1b);
    // gemm2: bufC = h1 @ Wg2^T
    gemm_rows<NHID><<<N_NODES / 8, 128, 0, stream>>>(bufB, Wg2, bufC);

    // agg2 + LN + relu -> latent(bufB), pool0 c0, LDS xc0 partials (1 row/wave)
    agg2_pool0<<<512, 1024, 0, stream>>>(row_start, esort, bufC, bufB,
                                         bg2, ln2g, ln2b, p0W, p0b, g0, c0, partials);

    // A0 pool + xc0 reduce + (after 266 producers) coarse solver, one kernel
    adjxc0_small<<<267, 256, 0, stream>>>(ei, ew, c0, A0, partials, xc0, sync + 1,
                                          g1, p1W, p1b, e0W, e0b, e1W, e1b,
                                          fcW, fcb, tbl);

    // final: out = latent @ fcA^T + tbl[c0]
    out_kernel<<<256, 256, 0, stream>>>(bufB, c0, tbl, fcW, out);
}

// Round 13
// 179.669 us; speedup vs baseline: 1.0181x; 1.0181x over previous
//
#include <hip/hip_runtime.h>

#define N_NODES 8192
#define N_EDGES 262144
#define NFEAT 200
#define NHID 128

// ---------------- GEMM body: C[8 rows,128] = A[8,K] @ W[128,K]^T ----------------
template<int K>
__device__ __forceinline__ void gemm_body(const float* __restrict__ A,
                                          const float* __restrict__ W,
                                          float* __restrict__ C, int bid) {
    __shared__ float a_s[8 * K];
    int row0 = bid * 8;
    const float* Ab = A + (size_t)row0 * K;
    for (int idx = threadIdx.x; idx < 8 * K; idx += 128) a_s[idx] = Ab[idx];
    __syncthreads();
    int j = threadIdx.x;
    float acc[8] = {0.f, 0.f, 0.f, 0.f, 0.f, 0.f, 0.f, 0.f};
    const float4* W4 = (const float4*)(W + (size_t)j * K);
    for (int k4 = 0; k4 < K / 4; ++k4) {
        float4 w = W4[k4];
        int k = k4 * 4;
        #pragma unroll
        for (int r = 0; r < 8; ++r) {
            const float* ar = a_s + r * K + k;
            acc[r] += ar[0] * w.x + ar[1] * w.y + ar[2] * w.z + ar[3] * w.w;
        }
    }
    #pragma unroll
    for (int r = 0; r < 8; ++r) C[(size_t)(row0 + r) * 128 + j] = acc[r];
}

template<int K>
__global__ __launch_bounds__(128) void gemm_rows(const float* __restrict__ A,
                                                 const float* __restrict__ W,
                                                 float* __restrict__ C) {
    gemm_body<K>(A, W, C, blockIdx.x);
}

// fused: blocks [0,512) gemm layer-1 (16 rows each); blocks [512,576) dst histogram
__global__ __launch_bounds__(128) void gemm1_hist(const float* __restrict__ A,
                                                  const float* __restrict__ W,
                                                  float* __restrict__ C,
                                                  const int* __restrict__ ei,
                                                  int* __restrict__ deg) {
    if (blockIdx.x < N_NODES / 16) {
        __shared__ float a_s[16 * NFEAT];
        int row0 = blockIdx.x * 16;
        const float* Ab = A + (size_t)row0 * NFEAT;
        for (int idx = threadIdx.x; idx < 16 * NFEAT; idx += 128) a_s[idx] = Ab[idx];
        __syncthreads();
        int j = threadIdx.x;
        float acc[16];
        #pragma unroll
        for (int r = 0; r < 16; ++r) acc[r] = 0.f;
        const float4* W4 = (const float4*)(W + (size_t)j * NFEAT);
        for (int k4 = 0; k4 < NFEAT / 4; ++k4) {
            float4 w = W4[k4];
            int k = k4 * 4;
            #pragma unroll
            for (int r = 0; r < 16; ++r) {
                const float* ar = a_s + r * NFEAT + k;
                acc[r] += ar[0] * w.x + ar[1] * w.y + ar[2] * w.z + ar[3] * w.w;
            }
        }
        #pragma unroll
        for (int r = 0; r < 16; ++r)
            C[(size_t)(row0 + r) * 128 + j] = acc[r];
    } else {
        const int* dst = ei + N_EDGES;
        for (int e = (blockIdx.x - N_NODES / 16) * 128 + threadIdx.x; e < N_EDGES; e += 64 * 128)
            atomicAdd(&deg[dst[e]], 1);
    }
}

// single block: parallel Hillis-Steele scan of deg[8192] -> row_start, cursor
// (R13: replaced tid==0 serial 256-iter dependent-LDS chain, ~13 us -> ~1 us)
__global__ __launch_bounds__(256) void scan_kernel(const int* __restrict__ deg,
                                                   int* __restrict__ row_start,
                                                   int* __restrict__ cursor) {
    __shared__ int part[256];
    int tid = threadIdx.x;
    int base = tid * 32;
    int s = 0;
    for (int i = 0; i < 32; ++i) s += deg[base + i];
    part[tid] = s;
    __syncthreads();
    for (int off = 1; off < 256; off <<= 1) {
        int v = (tid >= off) ? part[tid - off] : 0;
        __syncthreads();
        part[tid] += v;
        __syncthreads();
    }
    int run = part[tid] - s;                 // exclusive base of this 32-chunk
    for (int i = 0; i < 32; ++i) {
        int d = deg[base + i];
        row_start[base + i] = run;
        cursor[base + i] = run;
        run += d;
    }
    if (tid == 255) row_start[N_NODES] = part[255];
}

// scatter edges into dst-sorted order, packed (src, weight-bits)
__global__ __launch_bounds__(256) void scatter_kernel(const int* __restrict__ ei,
                                                      const float* __restrict__ ew,
                                                      int* __restrict__ cursor,
                                                      int2* __restrict__ esort, int E) {
    int e = blockIdx.x * blockDim.x + threadIdx.x;
    if (e < E) {
        int d = ei[E + e];
        int pos = atomicAdd(&cursor[d], 1);
        esort[pos] = make_int2(ei[e], __float_as_int(ew[e]));
    }
}

// weighted CSR gather, lane-parallel edge prefetch + shuffle broadcast
__device__ __forceinline__ float2 csr_gather(const int* __restrict__ row_start,
                                             const int2* __restrict__ esort,
                                             const float* __restrict__ H,
                                             int row, int lane) {
    int s0 = row_start[row], s1 = row_start[row + 1];
    float ax0 = 0.f, ay0 = 0.f, ax1 = 0.f, ay1 = 0.f;
    float ax2 = 0.f, ay2 = 0.f, ax3 = 0.f, ay3 = 0.f;
    for (int base = s0; base < s1; base += 64) {
        int n = s1 - base;
        if (n > 64) n = 64;
        int2 meta = make_int2(0, 0);
        if (lane < n) meta = esort[base + lane];
        int k = 0;
        for (; k + 3 < n; k += 4) {
            int sA = __shfl(meta.x, k, 64);
            int sB = __shfl(meta.x, k + 1, 64);
            int sC = __shfl(meta.x, k + 2, 64);
            int sD = __shfl(meta.x, k + 3, 64);
            float wA = __int_as_float(__shfl(meta.y, k, 64));
            float wB = __int_as_float(__shfl(meta.y, k + 1, 64));
            float wC = __int_as_float(__shfl(meta.y, k + 2, 64));
            float wD = __int_as_float(__shfl(meta.y, k + 3, 64));
            float2 vA = *(const float2*)(H + (size_t)sA * 128 + lane * 2);
            float2 vB = *(const float2*)(H + (size_t)sB * 128 + lane * 2);
            float2 vC = *(const float2*)(H + (size_t)sC * 128 + lane * 2);
            float2 vD = *(const float2*)(H + (size_t)sD * 128 + lane * 2);
            ax0 += wA * vA.x; ay0 += wA * vA.y;
            ax1 += wB * vB.x; ay1 += wB * vB.y;
            ax2 += wC * vC.x; ay2 += wC * vC.y;
            ax3 += wD * vD.x; ay3 += wD * vD.y;
        }
        for (; k < n; ++k) {
            int sA = __shfl(meta.x, k, 64);
            float wA = __int_as_float(__shfl(meta.y, k, 64));
            float2 vA = *(const float2*)(H + (size_t)sA * 128 + lane * 2);
            ax0 += wA * vA.x; ay0 += wA * vA.y;
        }
    }
    return make_float2((ax0 + ax1) + (ax2 + ax3), (ay0 + ay1) + (ay2 + ay3));
}

// bias + LayerNorm + relu on a wave-held row (2 dims/lane)
__device__ __forceinline__ float2 ln_relu(float vx, float vy, int lane,
                                          const float* __restrict__ bias,
                                          const float* __restrict__ g,
                                          const float* __restrict__ b) {
    float2 bs = *(const float2*)(bias + lane * 2);
    vx += bs.x; vy += bs.y;
    float s = vx + vy, ss = vx * vx + vy * vy;
    for (int off = 32; off; off >>= 1) {
        s += __shfl_xor(s, off, 64);
        ss += __shfl_xor(ss, off, 64);
    }
    float mu = s * (1.f / 128.f);
    float var = ss * (1.f / 128.f) - mu * mu;
    float rs = rsqrtf(var + 1e-5f);
    float2 gg = *(const float2*)(g + lane * 2);
    float2 bb = *(const float2*)(b + lane * 2);
    return make_float2(fmaxf((vx - mu) * rs * gg.x + bb.x, 0.f),
                       fmaxf((vy - mu) * rs * gg.y + bb.y, 0.f));
}

// ---------------- out[i] = relu(LN(agg(H)+bias)), one wave per row ----------------
__global__ __launch_bounds__(256) void agg_ln_csr(const int* __restrict__ row_start,
                                                  const int2* __restrict__ esort,
                                                  const float* __restrict__ H,
                                                  float* __restrict__ out,
                                                  const float* __restrict__ bias,
                                                  const float* __restrict__ g,
                                                  const float* __restrict__ b) {
    int wave = (blockIdx.x * blockDim.x + threadIdx.x) >> 6;
    int lane = threadIdx.x & 63;
    float2 a = csr_gather(row_start, esort, H, wave, lane);
    float2 y = ln_relu(a.x, a.y, lane, bias, g, b);
    *(float2*)(out + (size_t)wave * 128 + lane * 2) = y;
}

// ---------------- fused: latent = relu(LN(agg(bufC)+b)); pool0 c0; LDS xc0 partials ----
__global__ __launch_bounds__(1024) void agg2_pool0(const int* __restrict__ row_start,
                                                   const int2* __restrict__ esort,
                                                   const float* __restrict__ bufC,
                                                   float* __restrict__ latent,
                                                   const float* __restrict__ bias,
                                                   const float* __restrict__ g,
                                                   const float* __restrict__ b,
                                                   const float* __restrict__ p0W,
                                                   const float* __restrict__ p0b,
                                                   const float* __restrict__ gum,
                                                   int* __restrict__ c0,
                                                   float* __restrict__ partials) {
    __shared__ float Ws[1280];
    __shared__ float accs[1280];
    __shared__ float bsh[10];
    int tid = threadIdx.x;
    for (int i = tid; i < 1280; i += 1024) { Ws[i] = p0W[i]; accs[i] = 0.f; }
    if (tid < 10) bsh[tid] = p0b[tid];
    __syncthreads();
    int lane = tid & 63, wid = tid >> 6;
    int row = blockIdx.x * 16 + wid;
    float2 a = csr_gather(row_start, esort, bufC, row, lane);
    float2 y = ln_relu(a.x, a.y, lane, bias, g, b);
    *(float2*)(latent + (size_t)row * 128 + lane * 2) = y;
    float pk[10];
    #pragma unroll
    for (int k = 0; k < 10; ++k)
        pk[k] = y.x * Ws[k * 128 + lane * 2] + y.y * Ws[k * 128 + lane * 2 + 1];
    for (int off = 32; off; off >>= 1) {
        #pragma unroll
        for (int k = 0; k < 10; ++k) pk[k] += __shfl_xor(pk[k], off, 64);
    }
    const float* gr = gum + (size_t)row * 10;
    int best = 0;
    float bv = pk[0] + bsh[0] + gr[0];
    #pragma unroll
    for (int k = 1; k < 10; ++k) {
        float z = pk[k] + bsh[k] + gr[k];
        if (z > bv) { bv = z; best = k; }   // first max wins (jnp.argmax)
    }
    if (lane == 0) c0[row] = best;
    atomicAdd(&accs[best * 128 + lane * 2], y.x);
    atomicAdd(&accs[best * 128 + lane * 2 + 1], y.y);
    __syncthreads();
    for (int i = tid; i < 1280; i += 1024)
        partials[(size_t)blockIdx.x * 1280 + i] = accs[i];
}

// ---------------- fused: blocks [0,256) A0 edge-pool; blocks [256,266) xc0 reduce ----
__global__ __launch_bounds__(256) void adj_xc0(const int* __restrict__ ei,
                                               const float* __restrict__ ew,
                                               const int* __restrict__ c0,
                                               float* __restrict__ A0,
                                               const float* __restrict__ partials,
                                               float* __restrict__ xc0, int E) {
    if (blockIdx.x < 256) {
        __shared__ float As[100];
        for (int i = threadIdx.x; i < 100; i += 256) As[i] = 0.f;
        __syncthreads();
        for (int e = blockIdx.x * 256 + threadIdx.x; e < E; e += 256 * 256) {
            int a = c0[ei[e]], b = c0[ei[E + e]];
            atomicAdd(&As[a * 10 + b], ew[e]);
        }
        __syncthreads();
        for (int i = threadIdx.x; i < 100; i += 256) atomicAdd(&A0[i], As[i]);
    } else {
        int k = blockIdx.x - 256;
        int d = threadIdx.x & 127, half = threadIdx.x >> 7;
        float s0 = 0.f, s1 = 0.f, s2 = 0.f, s3 = 0.f;
        for (int b = half * 256; b < half * 256 + 256; b += 4) {
            s0 += partials[(size_t)(b    ) * 1280 + k * 128 + d];
            s1 += partials[(size_t)(b + 1) * 1280 + k * 128 + d];
            s2 += partials[(size_t)(b + 2) * 1280 + k * 128 + d];
            s3 += partials[(size_t)(b + 3) * 1280 + k * 128 + d];
        }
        __shared__ float sm[256];
        sm[threadIdx.x] = (s0 + s1) + (s2 + s3);
        __syncthreads();
        if (threadIdx.x < 128) xc0[k * 128 + d] = sm[threadIdx.x] + sm[threadIdx.x + 128];
    }
}

// ---------------- single-block 256 thr: coarse levels -> tbl[10][16] -----------------
// ALL weight matrices staged into LDS coalesced (uncoalesced row reads were 52 us)
__global__ __launch_bounds__(256) void small_kernel(const float* __restrict__ xc0,
                                                    const float* __restrict__ A0,
                                                    const float* __restrict__ gum1,
                                                    const float* __restrict__ p1W,
                                                    const float* __restrict__ p1b,
                                                    const float* __restrict__ e0W,
                                                    const float* __restrict__ e0b,
                                                    const float* __restrict__ e1W,
                                                    const float* __restrict__ e1b,
                                                    const float* __restrict__ fcW,
                                                    const float* __restrict__ fcb,
                                                    float* __restrict__ tbl) {
    __shared__ float Wst[64 * 129];    // 33 KB staging: e0W/e1W halves, p1W, fcW[:,128:384]
    __shared__ float xc0n[10 * 128];
    __shared__ float adj0[100];
    __shared__ float m0[10 * 128];
    __shared__ float l1[10 * 128];
    __shared__ float xc1n[5 * 128];
    __shared__ float l2[5 * 128];
    __shared__ float A1[25];
    __shared__ float lg[50];
    __shared__ int c1[10];
    __shared__ float red[4];

    int tid = threadIdx.x;
    int wid = tid >> 6, lane = tid & 63;

    // xc0 row-normalize
    for (int r = wid; r < 10; r += 4) {
        float2 v = *(const float2*)(xc0 + r * 128 + lane * 2);
        float ss = v.x * v.x + v.y * v.y;
        for (int off = 32; off; off >>= 1) ss += __shfl_xor(ss, off, 64);
        float sc = 1.f / fmaxf(sqrtf(ss), 1e-12f);
        xc0n[r * 128 + lane * 2] = v.x * sc;
        xc0n[r * 128 + lane * 2 + 1] = v.y * sc;
    }
    __syncthreads();
    if (tid == 0) {
        float s = 0.f;
        for (int i = 0; i < 100; ++i) s += A0[i];
        red[0] = s + 1e-6f;
    }
    __syncthreads();
    if (tid < 100) adj0[tid] = A0[tid] / red[0];
    __syncthreads();
    // m0 = adj0 @ xc0n
    for (int idx = tid; idx < 1280; idx += 256) {
        int r = idx >> 7, d = idx & 127;
        float acc = 0.f;
        #pragma unroll
        for (int a = 0; a < 10; ++a) acc += adj0[r * 10 + a] * xc0n[a * 128 + d];
        m0[idx] = acc;
    }
    __syncthreads();
    // l1 = relu(m0 @ e0W^T + e0b), e0W staged in two 64-row halves (stride 129: no conflicts)
    for (int h = 0; h < 2; ++h) {
        for (int i = tid; i < 64 * 128; i += 256)
            Wst[(i >> 7) * 129 + (i & 127)] = e0W[(size_t)(h * 64) * 128 + i];
        __syncthreads();
        for (int idx = tid; idx < 640; idx += 256) {
            int r = idx >> 6, dd = idx & 63;
            int d = h * 64 + dd;
            float acc = e0b[d];
            const float* wrow = Wst + dd * 129;
            const float* mr = m0 + r * 128;
            for (int k = 0; k < 128; ++k) acc += mr[k] * wrow[k];
            l1[r * 128 + d] = fmaxf(acc, 0.f);
        }
        __syncthreads();
    }
    // logits1 (50-thread parallel) + gumbel -> c1
    for (int i = tid; i < 640; i += 256) Wst[i] = p1W[i];
    __syncthreads();
    if (tid < 50) {
        int k = tid / 5, j = tid % 5;
        float acc = p1b[j] + gum1[k * 5 + j];
        const float* wrow = Wst + j * 128;
        const float* lr = l1 + k * 128;
        for (int kk = 0; kk < 128; ++kk) acc += lr[kk] * wrow[kk];
        lg[tid] = acc;
    }
    __syncthreads();
    if (tid < 10) {
        int best = 0;
        float bv = lg[tid * 5];
        for (int j = 1; j < 5; ++j) {
            float z = lg[tid * 5 + j];
            if (z > bv) { bv = z; best = j; }
        }
        c1[tid] = best;
    }
    __syncthreads();
    // xc1 = segsum(l1 by c1)
    for (int idx = tid; idx < 640; idx += 256) {
        int m = idx >> 7, d = idx & 127;
        float acc = 0.f;
        #pragma unroll
        for (int k = 0; k < 10; ++k)
            if (c1[k] == m) acc += l1[k * 128 + d];
        xc1n[idx] = acc;
    }
    __syncthreads();
    for (int r = wid; r < 5; r += 4) {
        float2 v = *(const float2*)(xc1n + r * 128 + lane * 2);
        float ss = v.x * v.x + v.y * v.y;
        for (int off = 32; off; off >>= 1) ss += __shfl_xor(ss, off, 64);
        float sc = 1.f / fmaxf(sqrtf(ss), 1e-12f);
        xc1n[r * 128 + lane * 2] = v.x * sc;
        xc1n[r * 128 + lane * 2 + 1] = v.y * sc;
    }
    __syncthreads();
    if (tid < 25) {
        int m = tid / 5, n = tid % 5;
        float acc = 0.f;
        for (int a = 0; a < 10; ++a)
            for (int b = 0; b < 10; ++b)
                if (c1[a] == m && c1[b] == n) acc += adj0[a * 10 + b];
        A1[tid] = acc;
    }
    __syncthreads();
    if (tid == 0) {
        float s = 0.f;
        for (int i = 0; i < 25; ++i) s += A1[i];
        red[1] = s + 25e-8f;
    }
    __syncthreads();
    float den1 = red[1];
    // m1 = (A1/den1) @ xc1n  (into m0)
    for (int idx = tid; idx < 640; idx += 256) {
        int r = idx >> 7, d = idx & 127;
        float acc = 0.f;
        #pragma unroll
        for (int a = 0; a < 5; ++a) acc += A1[r * 5 + a] * xc1n[a * 128 + d];
        m0[idx] = acc / den1;
    }
    __syncthreads();
    // l2 = relu(m1 @ e1W^T + e1b), staged halves
    for (int h = 0; h < 2; ++h) {
        for (int i = tid; i < 64 * 128; i += 256)
            Wst[(i >> 7) * 129 + (i & 127)] = e1W[(size_t)(h * 64) * 128 + i];
        __syncthreads();
        for (int idx = tid; idx < 320; idx += 256) {
            int r = idx >> 6, dd = idx & 63;
            int d = h * 64 + dd;
            float acc = e1b[d];
            const float* wrow = Wst + dd * 129;
            const float* mr = m0 + r * 128;
            for (int k = 0; k < 128; ++k) acc += mr[k] * wrow[k];
            l2[r * 128 + d] = fmaxf(acc, 0.f);
        }
        __syncthreads();
    }
    // stage fcW[:,128:384] as [16][257] (pad): fcs[o*257 + k2]
    for (int i = tid; i < 16 * 256; i += 256) {
        int o = i >> 8, k2 = i & 255;
        Wst[o * 257 + k2] = fcW[o * 384 + 128 + k2];
    }
    __syncthreads();
    // tbl[k][o] = fcb[o] + l1[k].fcB + l2[c1[k]].fcC
    for (int idx = tid; idx < 160; idx += 256) {
        int k = idx >> 4, o = idx & 15;
        float acc = fcb[o];
        const float* fB = Wst + o * 257;
        const float* fC = Wst + o * 257 + 128;
        const float* a1 = l1 + k * 128;
        const float* a2 = l2 + c1[k] * 128;
        for (int d = 0; d < 128; ++d) acc += a1[d] * fB[d] + a2[d] * fC[d];
        tbl[idx] = acc;
    }
}

// ---------------- out[i] = latent[i] @ fcA^T + tbl[c0[i]], 8-lane groups ----------------
__global__ __launch_bounds__(256) void out_kernel(const float* __restrict__ latent,
                                                  const int* __restrict__ c0,
                                                  const float* __restrict__ tbl,
                                                  const float* __restrict__ fcW,
                                                  float* __restrict__ out) {
    __shared__ float fA[16 * 128];
    __shared__ float ts[160];
    for (int i = threadIdx.x; i < 2048; i += 256) {
        int o = i >> 7, d = i & 127;
        fA[i] = fcW[o * 384 + d];
    }
    for (int i = threadIdx.x; i < 160; i += 256) ts[i] = tbl[i];
    __syncthreads();
    int lane = threadIdx.x & 63;
    int sub = lane & 7;
    int row = blockIdx.x * 32 + (threadIdx.x >> 6) * 8 + (lane >> 3);
    const float4* lp = (const float4*)(latent + (size_t)row * 128 + sub * 16);
    float4 x0 = lp[0], x1 = lp[1], x2 = lp[2], x3 = lp[3];
    float p[16];
    #pragma unroll
    for (int o = 0; o < 16; ++o) {
        const float4* fo = (const float4*)(fA + o * 128 + sub * 16);
        float4 w0 = fo[0], w1 = fo[1], w2 = fo[2], w3 = fo[3];
        float a = x0.x * w0.x + x0.y * w0.y + x0.z * w0.z + x0.w * w0.w;
        a += x1.x * w1.x + x1.y * w1.y + x1.z * w1.z + x1.w * w1.w;
        a += x2.x * w2.x + x2.y * w2.y + x2.z * w2.z + x2.w * w2.w;
        a += x3.x * w3.x + x3.y * w3.y + x3.z * w3.z + x3.w * w3.w;
        p[o] = a;
    }
    #pragma unroll
    for (int off = 1; off < 8; off <<= 1) {
        #pragma unroll
        for (int o = 0; o < 16; ++o) p[o] += __shfl_xor(p[o], off, 64);
    }
    int c = c0[row];
    float2 r = make_float2(p[2 * sub] + ts[c * 16 + 2 * sub],
                           p[2 * sub + 1] + ts[c * 16 + 2 * sub + 1]);
    *(float2*)(out + (size_t)row * 16 + 2 * sub) = r;
}

extern "C" void kernel_launch(void* const* d_in, const int* in_sizes, int n_in,
                              void* d_out, int out_size, void* d_ws, size_t ws_size,
                              hipStream_t stream) {
    const float* x    = (const float*)d_in[0];
    const int*   ei   = (const int*)d_in[1];
    const float* ew   = (const float*)d_in[2];
    const float* g0   = (const float*)d_in[3];
    const float* g1   = (const float*)d_in[4];
    const float* Wg1  = (const float*)d_in[5];
    const float* bg1  = (const float*)d_in[6];
    const float* ln1g = (const float*)d_in[7];
    const float* ln1b = (const float*)d_in[8];
    const float* Wg2  = (const float*)d_in[9];
    const float* bg2  = (const float*)d_in[10];
    const float* ln2g = (const float*)d_in[11];
    const float* ln2b = (const float*)d_in[12];
    const float* p0W  = (const float*)d_in[13];
    const float* p0b  = (const float*)d_in[14];
    const float* p1W  = (const float*)d_in[15];
    const float* p1b  = (const float*)d_in[16];
    const float* e0W  = (const float*)d_in[17];
    const float* e0b  = (const float*)d_in[18];
    const float* e1W  = (const float*)d_in[19];
    const float* e1b  = (const float*)d_in[20];
    const float* fcW  = (const float*)d_in[21];
    const float* fcb  = (const float*)d_in[22];
    float* out = (float*)d_out;

    float* ws   = (float*)d_ws;
    float* bufA = ws;                                        // N*128 f (gemm1 out)
    float* bufB = bufA + (size_t)N_NODES * 128;              // N*128 f (latent / h1)
    float* bufC = bufB + (size_t)N_NODES * 128;              // N*128 f (gemm2 out)
    int*   c0   = (int*)(bufC + (size_t)N_NODES * 128);      // N int
    float* xc0  = (float*)(c0 + N_NODES);                    // 1280 f
    float* tbl  = xc0 + 1280;                                // 160 f
    int*   deg  = (int*)(tbl + 160);                         // 8192 int   <- memset start
    float* A0   = (float*)(deg + N_NODES);                   // 100 f      <- contiguous
    int*   row_start = (int*)(A0 + 100);                     // 8194 int
    int*   cursor    = row_start + N_NODES + 2;              // 8192 int
    int2*  esort     = (int2*)(cursor + N_NODES);            // E int2
    float* partials  = bufA;   // 512*1280 f, reuses bufA (dead after gemm2)

    // zero deg + A0 in one fill
    hipMemsetAsync(deg, 0, (N_NODES + 100) * sizeof(int), stream);

    // layer-1 gemm (16 rows/block; agg commutes) fused with dst-histogram
    gemm1_hist<<<N_NODES / 16 + 64, 128, 0, stream>>>(x, Wg1, bufA, ei, deg);
    scan_kernel<<<1, 256, 0, stream>>>(deg, row_start, cursor);
    scatter_kernel<<<N_EDGES / 256, 256, 0, stream>>>(ei, ew, cursor, esort, N_EDGES);

    // agg1 + LN + relu -> bufB (h1)
    agg_ln_csr<<<N_NODES / 4, 256, 0, stream>>>(row_start, esort, bufA, bufB,
                                                bg1, ln1g, ln1b);
    // gemm2: bufC = h1 @ Wg2^T
    gemm_rows<NHID><<<N_NODES / 8, 128, 0, stream>>>(bufB, Wg2, bufC);

    // agg2 + LN + relu -> latent(bufB), pool0 c0, LDS xc0 partials (1 row/wave)
    agg2_pool0<<<512, 1024, 0, stream>>>(row_start, esort, bufC, bufB,
                                         bg2, ln2g, ln2b, p0W, p0b, g0, c0, partials);

    // A0 edge-pool + xc0 reduce (independent block ranges)
    adj_xc0<<<266, 256, 0, stream>>>(ei, ew, c0, A0, partials, xc0, N_EDGES);

    // coarse levels -> tbl (LDS-staged weights)
    small_kernel<<<1, 256, 0, stream>>>(xc0, A0, g1, p1W, p1b, e0W, e0b, e1W, e1b,
                                        fcW, fcb, tbl);

    // final: out = latent @ fcA^T + tbl[c0]
    out_kernel<<<256, 256, 0, stream>>>(bufB, c0, tbl, fcW, out);
}

// Round 14
// 173.024 us; speedup vs baseline: 1.0572x; 1.0384x over previous
//
#include <hip/hip_runtime.h>

#define N_NODES 8192
#define N_EDGES 262144
#define NFEAT 200
#define NHID 128

// ---------------- GEMM body: C[8 rows,128] = A[8,K] @ W[128,K]^T ----------------
template<int K>
__device__ __forceinline__ void gemm_body(const float* __restrict__ A,
                                          const float* __restrict__ W,
                                          float* __restrict__ C, int bid) {
    __shared__ float a_s[8 * K];
    int row0 = bid * 8;
    const float* Ab = A + (size_t)row0 * K;
    for (int idx = threadIdx.x; idx < 8 * K; idx += 128) a_s[idx] = Ab[idx];
    __syncthreads();
    int j = threadIdx.x;
    float acc[8] = {0.f, 0.f, 0.f, 0.f, 0.f, 0.f, 0.f, 0.f};
    const float4* W4 = (const float4*)(W + (size_t)j * K);
    for (int k4 = 0; k4 < K / 4; ++k4) {
        float4 w = W4[k4];
        int k = k4 * 4;
        #pragma unroll
        for (int r = 0; r < 8; ++r) {
            const float* ar = a_s + r * K + k;
            acc[r] += ar[0] * w.x + ar[1] * w.y + ar[2] * w.z + ar[3] * w.w;
        }
    }
    #pragma unroll
    for (int r = 0; r < 8; ++r) C[(size_t)(row0 + r) * 128 + j] = acc[r];
}

template<int K>
__global__ __launch_bounds__(128) void gemm_rows(const float* __restrict__ A,
                                                 const float* __restrict__ W,
                                                 float* __restrict__ C) {
    gemm_body<K>(A, W, C, blockIdx.x);
}

// fused: blocks [0,1024) gemm layer-1; blocks [1024,1088) histogram of dst
__global__ __launch_bounds__(128) void gemm1_hist(const float* __restrict__ A,
                                                  const float* __restrict__ W,
                                                  float* __restrict__ C,
                                                  const int* __restrict__ ei,
                                                  int* __restrict__ deg) {
    if (blockIdx.x < N_NODES / 8) {
        gemm_body<NFEAT>(A, W, C, blockIdx.x);
    } else {
        const int* dst = ei + N_EDGES;
        for (int e = (blockIdx.x - N_NODES / 8) * 128 + threadIdx.x; e < N_EDGES; e += 64 * 128)
            atomicAdd(&deg[dst[e]], 1);
    }
}

// single block: parallel Hillis-Steele scan of deg[8192] -> row_start, cursor
__global__ __launch_bounds__(256) void scan_kernel(const int* __restrict__ deg,
                                                   int* __restrict__ row_start,
                                                   int* __restrict__ cursor) {
    __shared__ int part[256];
    int tid = threadIdx.x;
    int base = tid * 32;
    int s = 0;
    for (int i = 0; i < 32; ++i) s += deg[base + i];
    part[tid] = s;
    __syncthreads();
    for (int off = 1; off < 256; off <<= 1) {
        int v = (tid >= off) ? part[tid - off] : 0;
        __syncthreads();
        part[tid] += v;
        __syncthreads();
    }
    int run = part[tid] - s;                 // exclusive base of this 32-chunk
    for (int i = 0; i < 32; ++i) {
        int d = deg[base + i];
        row_start[base + i] = run;
        cursor[base + i] = run;
        run += d;
    }
    if (tid == 255) row_start[N_NODES] = part[255];
}

// scatter edges into dst-sorted order, packed (src, weight-bits)
__global__ __launch_bounds__(256) void scatter_kernel(const int* __restrict__ ei,
                                                      const float* __restrict__ ew,
                                                      int* __restrict__ cursor,
                                                      int2* __restrict__ esort, int E) {
    int e = blockIdx.x * blockDim.x + threadIdx.x;
    if (e < E) {
        int d = ei[E + e];
        int pos = atomicAdd(&cursor[d], 1);
        esort[pos] = make_int2(ei[e], __float_as_int(ew[e]));
    }
}

// weighted CSR gather, lane-parallel edge prefetch + shuffle broadcast
__device__ __forceinline__ float2 csr_gather(const int* __restrict__ row_start,
                                             const int2* __restrict__ esort,
                                             const float* __restrict__ H,
                                             int row, int lane) {
    int s0 = row_start[row], s1 = row_start[row + 1];
    float ax0 = 0.f, ay0 = 0.f, ax1 = 0.f, ay1 = 0.f;
    float ax2 = 0.f, ay2 = 0.f, ax3 = 0.f, ay3 = 0.f;
    for (int base = s0; base < s1; base += 64) {
        int n = s1 - base;
        if (n > 64) n = 64;
        int2 meta = make_int2(0, 0);
        if (lane < n) meta = esort[base + lane];
        int k = 0;
        for (; k + 3 < n; k += 4) {
            int sA = __shfl(meta.x, k, 64);
            int sB = __shfl(meta.x, k + 1, 64);
            int sC = __shfl(meta.x, k + 2, 64);
            int sD = __shfl(meta.x, k + 3, 64);
            float wA = __int_as_float(__shfl(meta.y, k, 64));
            float wB = __int_as_float(__shfl(meta.y, k + 1, 64));
            float wC = __int_as_float(__shfl(meta.y, k + 2, 64));
            float wD = __int_as_float(__shfl(meta.y, k + 3, 64));
            float2 vA = *(const float2*)(H + (size_t)sA * 128 + lane * 2);
            float2 vB = *(const float2*)(H + (size_t)sB * 128 + lane * 2);
            float2 vC = *(const float2*)(H + (size_t)sC * 128 + lane * 2);
            float2 vD = *(const float2*)(H + (size_t)sD * 128 + lane * 2);
            ax0 += wA * vA.x; ay0 += wA * vA.y;
            ax1 += wB * vB.x; ay1 += wB * vB.y;
            ax2 += wC * vC.x; ay2 += wC * vC.y;
            ax3 += wD * vD.x; ay3 += wD * vD.y;
        }
        for (; k < n; ++k) {
            int sA = __shfl(meta.x, k, 64);
            float wA = __int_as_float(__shfl(meta.y, k, 64));
            float2 vA = *(const float2*)(H + (size_t)sA * 128 + lane * 2);
            ax0 += wA * vA.x; ay0 += wA * vA.y;
        }
    }
    return make_float2((ax0 + ax1) + (ax2 + ax3), (ay0 + ay1) + (ay2 + ay3));
}

// bias + LayerNorm + relu on a wave-held row (2 dims/lane)
__device__ __forceinline__ float2 ln_relu(float vx, float vy, int lane,
                                          const float* __restrict__ bias,
                                          const float* __restrict__ g,
                                          const float* __restrict__ b) {
    float2 bs = *(const float2*)(bias + lane * 2);
    vx += bs.x; vy += bs.y;
    float s = vx + vy, ss = vx * vx + vy * vy;
    for (int off = 32; off; off >>= 1) {
        s += __shfl_xor(s, off, 64);
        ss += __shfl_xor(ss, off, 64);
    }
    float mu = s * (1.f / 128.f);
    float var = ss * (1.f / 128.f) - mu * mu;
    float rs = rsqrtf(var + 1e-5f);
    float2 gg = *(const float2*)(g + lane * 2);
    float2 bb = *(const float2*)(b + lane * 2);
    return make_float2(fmaxf((vx - mu) * rs * gg.x + bb.x, 0.f),
                       fmaxf((vy - mu) * rs * gg.y + bb.y, 0.f));
}

// ---------------- out[i] = relu(LN(agg(H)+bias)), one wave per row ----------------
__global__ __launch_bounds__(256) void agg_ln_csr(const int* __restrict__ row_start,
                                                  const int2* __restrict__ esort,
                                                  const float* __restrict__ H,
                                                  float* __restrict__ out,
                                                  const float* __restrict__ bias,
                                                  const float* __restrict__ g,
                                                  const float* __restrict__ b) {
    int wave = (blockIdx.x * blockDim.x + threadIdx.x) >> 6;
    int lane = threadIdx.x & 63;
    float2 a = csr_gather(row_start, esort, H, wave, lane);
    float2 y = ln_relu(a.x, a.y, lane, bias, g, b);
    *(float2*)(out + (size_t)wave * 128 + lane * 2) = y;
}

// ---------------- fused: latent = relu(LN(agg(bufC)+b)); pool0 c0; LDS xc0 partials ----
__global__ __launch_bounds__(1024) void agg2_pool0(const int* __restrict__ row_start,
                                                   const int2* __restrict__ esort,
                                                   const float* __restrict__ bufC,
                                                   float* __restrict__ latent,
                                                   const float* __restrict__ bias,
                                                   const float* __restrict__ g,
                                                   const float* __restrict__ b,
                                                   const float* __restrict__ p0W,
                                                   const float* __restrict__ p0b,
                                                   const float* __restrict__ gum,
                                                   int* __restrict__ c0,
                                                   float* __restrict__ partials) {
    __shared__ float Ws[1280];
    __shared__ float accs[1280];
    __shared__ float bsh[10];
    int tid = threadIdx.x;
    for (int i = tid; i < 1280; i += 1024) { Ws[i] = p0W[i]; accs[i] = 0.f; }
    if (tid < 10) bsh[tid] = p0b[tid];
    __syncthreads();
    int lane = tid & 63, wid = tid >> 6;
    int row = blockIdx.x * 16 + wid;
    float2 a = csr_gather(row_start, esort, bufC, row, lane);
    float2 y = ln_relu(a.x, a.y, lane, bias, g, b);
    *(float2*)(latent + (size_t)row * 128 + lane * 2) = y;
    float pk[10];
    #pragma unroll
    for (int k = 0; k < 10; ++k)
        pk[k] = y.x * Ws[k * 128 + lane * 2] + y.y * Ws[k * 128 + lane * 2 + 1];
    for (int off = 32; off; off >>= 1) {
        #pragma unroll
        for (int k = 0; k < 10; ++k) pk[k] += __shfl_xor(pk[k], off, 64);
    }
    const float* gr = gum + (size_t)row * 10;
    int best = 0;
    float bv = pk[0] + bsh[0] + gr[0];
    #pragma unroll
    for (int k = 1; k < 10; ++k) {
        float z = pk[k] + bsh[k] + gr[k];
        if (z > bv) { bv = z; best = k; }   // first max wins (jnp.argmax)
    }
    if (lane == 0) c0[row] = best;
    atomicAdd(&accs[best * 128 + lane * 2], y.x);
    atomicAdd(&accs[best * 128 + lane * 2 + 1], y.y);
    __syncthreads();
    for (int i = tid; i < 1280; i += 1024)
        partials[(size_t)blockIdx.x * 1280 + i] = accs[i];
}

// ---------------- fused: blocks [0,256) A0 edge-pool; blocks [256,266) xc0 reduce ----
__global__ __launch_bounds__(256) void adj_xc0(const int* __restrict__ ei,
                                               const float* __restrict__ ew,
                                               const int* __restrict__ c0,
                                               float* __restrict__ A0,
                                               const float* __restrict__ partials,
                                               float* __restrict__ xc0, int E) {
    if (blockIdx.x < 256) {
        __shared__ float As[100];
        for (int i = threadIdx.x; i < 100; i += 256) As[i] = 0.f;
        __syncthreads();
        for (int e = blockIdx.x * 256 + threadIdx.x; e < E; e += 256 * 256) {
            int a = c0[ei[e]], b = c0[ei[E + e]];
            atomicAdd(&As[a * 10 + b], ew[e]);
        }
        __syncthreads();
        for (int i = threadIdx.x; i < 100; i += 256) atomicAdd(&A0[i], As[i]);
    } else {
        int k = blockIdx.x - 256;
        int d = threadIdx.x & 127, half = threadIdx.x >> 7;
        float s0 = 0.f, s1 = 0.f, s2 = 0.f, s3 = 0.f;
        for (int b = half * 256; b < half * 256 + 256; b += 4) {
            s0 += partials[(size_t)(b    ) * 1280 + k * 128 + d];
            s1 += partials[(size_t)(b + 1) * 1280 + k * 128 + d];
            s2 += partials[(size_t)(b + 2) * 1280 + k * 128 + d];
            s3 += partials[(size_t)(b + 3) * 1280 + k * 128 + d];
        }
        __shared__ float sm[256];
        sm[threadIdx.x] = (s0 + s1) + (s2 + s3);
        __syncthreads();
        if (threadIdx.x < 128) xc0[k * 128 + d] = sm[threadIdx.x] + sm[threadIdx.x + 128];
    }
}

// ---------------- single-block 256 thr: coarse levels -> tbl[10][16] -----------------
// ALL weight matrices staged into LDS coalesced (uncoalesced row reads were 52 us)
__global__ __launch_bounds__(256) void small_kernel(const float* __restrict__ xc0,
                                                    const float* __restrict__ A0,
                                                    const float* __restrict__ gum1,
                                                    const float* __restrict__ p1W,
                                                    const float* __restrict__ p1b,
                                                    const float* __restrict__ e0W,
                                                    const float* __restrict__ e0b,
                                                    const float* __restrict__ e1W,
                                                    const float* __restrict__ e1b,
                                                    const float* __restrict__ fcW,
                                                    const float* __restrict__ fcb,
                                                    float* __restrict__ tbl) {
    __shared__ float Wst[64 * 129];    // 33 KB staging: e0W/e1W halves, p1W, fcW[:,128:384]
    __shared__ float xc0n[10 * 128];
    __shared__ float adj0[100];
    __shared__ float m0[10 * 128];
    __shared__ float l1[10 * 128];
    __shared__ float xc1n[5 * 128];
    __shared__ float l2[5 * 128];
    __shared__ float A1[25];
    __shared__ float lg[50];
    __shared__ int c1[10];
    __shared__ float red[4];

    int tid = threadIdx.x;
    int wid = tid >> 6, lane = tid & 63;

    // xc0 row-normalize
    for (int r = wid; r < 10; r += 4) {
        float2 v = *(const float2*)(xc0 + r * 128 + lane * 2);
        float ss = v.x * v.x + v.y * v.y;
        for (int off = 32; off; off >>= 1) ss += __shfl_xor(ss, off, 64);
        float sc = 1.f / fmaxf(sqrtf(ss), 1e-12f);
        xc0n[r * 128 + lane * 2] = v.x * sc;
        xc0n[r * 128 + lane * 2 + 1] = v.y * sc;
    }
    __syncthreads();
    if (tid == 0) {
        float s = 0.f;
        for (int i = 0; i < 100; ++i) s += A0[i];
        red[0] = s + 1e-6f;
    }
    __syncthreads();
    if (tid < 100) adj0[tid] = A0[tid] / red[0];
    __syncthreads();
    // m0 = adj0 @ xc0n
    for (int idx = tid; idx < 1280; idx += 256) {
        int r = idx >> 7, d = idx & 127;
        float acc = 0.f;
        #pragma unroll
        for (int a = 0; a < 10; ++a) acc += adj0[r * 10 + a] * xc0n[a * 128 + d];
        m0[idx] = acc;
    }
    __syncthreads();
    // l1 = relu(m0 @ e0W^T + e0b), e0W staged in two 64-row halves (stride 129: no conflicts)
    for (int h = 0; h < 2; ++h) {
        for (int i = tid; i < 64 * 128; i += 256)
            Wst[(i >> 7) * 129 + (i & 127)] = e0W[(size_t)(h * 64) * 128 + i];
        __syncthreads();
        for (int idx = tid; idx < 640; idx += 256) {
            int r = idx >> 6, dd = idx & 63;
            int d = h * 64 + dd;
            float acc = e0b[d];
            const float* wrow = Wst + dd * 129;
            const float* mr = m0 + r * 128;
            for (int k = 0; k < 128; ++k) acc += mr[k] * wrow[k];
            l1[r * 128 + d] = fmaxf(acc, 0.f);
        }
        __syncthreads();
    }
    // logits1 (50-thread parallel) + gumbel -> c1
    for (int i = tid; i < 640; i += 256) Wst[i] = p1W[i];
    __syncthreads();
    if (tid < 50) {
        int k = tid / 5, j = tid % 5;
        float acc = p1b[j] + gum1[k * 5 + j];
        const float* wrow = Wst + j * 128;
        const float* lr = l1 + k * 128;
        for (int kk = 0; kk < 128; ++kk) acc += lr[kk] * wrow[kk];
        lg[tid] = acc;
    }
    __syncthreads();
    if (tid < 10) {
        int best = 0;
        float bv = lg[tid * 5];
        for (int j = 1; j < 5; ++j) {
            float z = lg[tid * 5 + j];
            if (z > bv) { bv = z; best = j; }
        }
        c1[tid] = best;
    }
    __syncthreads();
    // xc1 = segsum(l1 by c1)
    for (int idx = tid; idx < 640; idx += 256) {
        int m = idx >> 7, d = idx & 127;
        float acc = 0.f;
        #pragma unroll
        for (int k = 0; k < 10; ++k)
            if (c1[k] == m) acc += l1[k * 128 + d];
        xc1n[idx] = acc;
    }
    __syncthreads();
    for (int r = wid; r < 5; r += 4) {
        float2 v = *(const float2*)(xc1n + r * 128 + lane * 2);
        float ss = v.x * v.x + v.y * v.y;
        for (int off = 32; off; off >>= 1) ss += __shfl_xor(ss, off, 64);
        float sc = 1.f / fmaxf(sqrtf(ss), 1e-12f);
        xc1n[r * 128 + lane * 2] = v.x * sc;
        xc1n[r * 128 + lane * 2 + 1] = v.y * sc;
    }
    __syncthreads();
    if (tid < 25) {
        int m = tid / 5, n = tid % 5;
        float acc = 0.f;
        for (int a = 0; a < 10; ++a)
            for (int b = 0; b < 10; ++b)
                if (c1[a] == m && c1[b] == n) acc += adj0[a * 10 + b];
        A1[tid] = acc;
    }
    __syncthreads();
    if (tid == 0) {
        float s = 0.f;
        for (int i = 0; i < 25; ++i) s += A1[i];
        red[1] = s + 25e-8f;
    }
    __syncthreads();
    float den1 = red[1];
    // m1 = (A1/den1) @ xc1n  (into m0)
    for (int idx = tid; idx < 640; idx += 256) {
        int r = idx >> 7, d = idx & 127;
        float acc = 0.f;
        #pragma unroll
        for (int a = 0; a < 5; ++a) acc += A1[r * 5 + a] * xc1n[a * 128 + d];
        m0[idx] = acc / den1;
    }
    __syncthreads();
    // l2 = relu(m1 @ e1W^T + e1b), staged halves
    for (int h = 0; h < 2; ++h) {
        for (int i = tid; i < 64 * 128; i += 256)
            Wst[(i >> 7) * 129 + (i & 127)] = e1W[(size_t)(h * 64) * 128 + i];
        __syncthreads();
        for (int idx = tid; idx < 320; idx += 256) {
            int r = idx >> 6, dd = idx & 63;
            int d = h * 64 + dd;
            float acc = e1b[d];
            const float* wrow = Wst + dd * 129;
            const float* mr = m0 + r * 128;
            for (int k = 0; k < 128; ++k) acc += mr[k] * wrow[k];
            l2[r * 128 + d] = fmaxf(acc, 0.f);
        }
        __syncthreads();
    }
    // stage fcW[:,128:384] as [16][257] (pad): fcs[o*257 + k2]
    for (int i = tid; i < 16 * 256; i += 256) {
        int o = i >> 8, k2 = i & 255;
        Wst[o * 257 + k2] = fcW[o * 384 + 128 + k2];
    }
    __syncthreads();
    // tbl[k][o] = fcb[o] + l1[k].fcB + l2[c1[k]].fcC
    for (int idx = tid; idx < 160; idx += 256) {
        int k = idx >> 4, o = idx & 15;
        float acc = fcb[o];
        const float* fB = Wst + o * 257;
        const float* fC = Wst + o * 257 + 128;
        const float* a1 = l1 + k * 128;
        const float* a2 = l2 + c1[k] * 128;
        for (int d = 0; d < 128; ++d) acc += a1[d] * fB[d] + a2[d] * fC[d];
        tbl[idx] = acc;
    }
}

// ---------------- out[i] = latent[i] @ fcA^T + tbl[c0[i]], 8-lane groups ----------------
__global__ __launch_bounds__(256) void out_kernel(const float* __restrict__ latent,
                                                  const int* __restrict__ c0,
                                                  const float* __restrict__ tbl,
                                                  const float* __restrict__ fcW,
                                                  float* __restrict__ out) {
    __shared__ float fA[16 * 128];
    __shared__ float ts[160];
    for (int i = threadIdx.x; i < 2048; i += 256) {
        int o = i >> 7, d = i & 127;
        fA[i] = fcW[o * 384 + d];
    }
    for (int i = threadIdx.x; i < 160; i += 256) ts[i] = tbl[i];
    __syncthreads();
    int lane = threadIdx.x & 63;
    int sub = lane & 7;
    int row = blockIdx.x * 32 + (threadIdx.x >> 6) * 8 + (lane >> 3);
    const float4* lp = (const float4*)(latent + (size_t)row * 128 + sub * 16);
    float4 x0 = lp[0], x1 = lp[1], x2 = lp[2], x3 = lp[3];
    float p[16];
    #pragma unroll
    for (int o = 0; o < 16; ++o) {
        const float4* fo = (const float4*)(fA + o * 128 + sub * 16);
        float4 w0 = fo[0], w1 = fo[1], w2 = fo[2], w3 = fo[3];
        float a = x0.x * w0.x + x0.y * w0.y + x0.z * w0.z + x0.w * w0.w;
        a += x1.x * w1.x + x1.y * w1.y + x1.z * w1.z + x1.w * w1.w;
        a += x2.x * w2.x + x2.y * w2.y + x2.z * w2.z + x2.w * w2.w;
        a += x3.x * w3.x + x3.y * w3.y + x3.z * w3.z + x3.w * w3.w;
        p[o] = a;
    }
    #pragma unroll
    for (int off = 1; off < 8; off <<= 1) {
        #pragma unroll
        for (int o = 0; o < 16; ++o) p[o] += __shfl_xor(p[o], off, 64);
    }
    int c = c0[row];
    float2 r = make_float2(p[2 * sub] + ts[c * 16 + 2 * sub],
                           p[2 * sub + 1] + ts[c * 16 + 2 * sub + 1]);
    *(float2*)(out + (size_t)row * 16 + 2 * sub) = r;
}

extern "C" void kernel_launch(void* const* d_in, const int* in_sizes, int n_in,
                              void* d_out, int out_size, void* d_ws, size_t ws_size,
                              hipStream_t stream) {
    const float* x    = (const float*)d_in[0];
    const int*   ei   = (const int*)d_in[1];
    const float* ew   = (const float*)d_in[2];
    const float* g0   = (const float*)d_in[3];
    const float* g1   = (const float*)d_in[4];
    const float* Wg1  = (const float*)d_in[5];
    const float* bg1  = (const float*)d_in[6];
    const float* ln1g = (const float*)d_in[7];
    const float* ln1b = (const float*)d_in[8];
    const float* Wg2  = (const float*)d_in[9];
    const float* bg2  = (const float*)d_in[10];
    const float* ln2g = (const float*)d_in[11];
    const float* ln2b = (const float*)d_in[12];
    const float* p0W  = (const float*)d_in[13];
    const float* p0b  = (const float*)d_in[14];
    const float* p1W  = (const float*)d_in[15];
    const float* p1b  = (const float*)d_in[16];
    const float* e0W  = (const float*)d_in[17];
    const float* e0b  = (const float*)d_in[18];
    const float* e1W  = (const float*)d_in[19];
    const float* e1b  = (const float*)d_in[20];
    const float* fcW  = (const float*)d_in[21];
    const float* fcb  = (const float*)d_in[22];
    float* out = (float*)d_out;

    float* ws   = (float*)d_ws;
    float* bufA = ws;                                        // N*128 f (gemm1 out)
    float* bufB = bufA + (size_t)N_NODES * 128;              // N*128 f (latent / h1)
    float* bufC = bufB + (size_t)N_NODES * 128;              // N*128 f (gemm2 out)
    int*   c0   = (int*)(bufC + (size_t)N_NODES * 128);      // N int
    float* xc0  = (float*)(c0 + N_NODES);                    // 1280 f
    float* tbl  = xc0 + 1280;                                // 160 f
    int*   deg  = (int*)(tbl + 160);                         // 8192 int   <- memset start
    float* A0   = (float*)(deg + N_NODES);                   // 100 f      <- contiguous
    int*   row_start = (int*)(A0 + 100);                     // 8194 int
    int*   cursor    = row_start + N_NODES + 2;              // 8192 int
    int2*  esort     = (int2*)(cursor + N_NODES);            // E int2
    float* partials  = bufA;   // 512*1280 f, reuses bufA (dead after gemm2)

    // zero deg + A0 in one fill
    hipMemsetAsync(deg, 0, (N_NODES + 100) * sizeof(int), stream);

    // layer-1 gemm (agg commutes) fused with dst-histogram
    gemm1_hist<<<N_NODES / 8 + 64, 128, 0, stream>>>(x, Wg1, bufA, ei, deg);
    scan_kernel<<<1, 256, 0, stream>>>(deg, row_start, cursor);
    scatter_kernel<<<N_EDGES / 256, 256, 0, stream>>>(ei, ew, cursor, esort, N_EDGES);

    // agg1 + LN + relu -> bufB (h1)
    agg_ln_csr<<<N_NODES / 4, 256, 0, stream>>>(row_start, esort, bufA, bufB,
                                                bg1, ln1g, ln1b);
    // gemm2: bufC = h1 @ Wg2^T
    gemm_rows<NHID><<<N_NODES / 8, 128, 0, stream>>>(bufB, Wg2, bufC);

    // agg2 + LN + relu -> latent(bufB), pool0 c0, LDS xc0 partials (1 row/wave)
    agg2_pool0<<<512, 1024, 0, stream>>>(row_start, esort, bufC, bufB,
                                         bg2, ln2g, ln2b, p0W, p0b, g0, c0, partials);

    // A0 edge-pool + xc0 reduce (independent block ranges)
    adj_xc0<<<266, 256, 0, stream>>>(ei, ew, c0, A0, partials, xc0, N_EDGES);

    // coarse levels -> tbl (LDS-staged weights)
    small_kernel<<<1, 256, 0, stream>>>(xc0, A0, g1, p1W, p1b, e0W, e0b, e1W, e1b,
                                        fcW, fcb, tbl);

    // final: out = latent @ fcA^T + tbl[c0]
    out_kernel<<<256, 256, 0, stream>>>(bufB, c0, tbl, fcW, out);
}